// Round 3
// baseline (472.427 us; speedup 1.0000x reference)
//
#include <hip/hip_runtime.h>
#include <hip/hip_fp16.h>
#include <cmath>

// ---------------------------------------------------------------------------
// Self_Attention: B=8, C=256, C_=32, H=W=64, N=4096, GAMMA=1.0
// R7: barrier-free pass2. Every wave computes the full 64x64 S tile and
// keeps P in REGISTERS (no LDS, no __syncthreads):
//   - S via mfma_f32_16x16x32_f16 -> d layout: lane(col,q) holds
//     (i=16it+col, j=16jt+4q+r), r=0..3  [HW-verified by R5's P indexing]
//   - O via mfma_f32_16x16x16_f16 whose A-frag layout A[m=col][k=4q+e]
//     EXACTLY matches d -> exp2 + f16 cast, zero cross-lane ops
//   - hv = 16 b64 loads (B-frag k=4q+e), double-buffered one full step
//   - linv folded into exp2 addend: pass1 stores shl[j] = -log2(l)-SHIFT2,
//     P = exp2(S*log2e + shl[j])  (bit-equivalent math, one less VALU op)
// Cost: x4 redundant S/exp per block (waves no longer share P) - bought
// barrier-free free-running waves; all latency hidden by in-wave ILP.
// ws: xt 16M | wf 256K | ft 2M | gt 2M | hm 16M | shl 128K
// ---------------------------------------------------------------------------

#define BN 8
#define CC 256
#define CQ 32
#define NN 4096

typedef _Float16 half8 __attribute__((ext_vector_type(8)));
typedef _Float16 half4v __attribute__((ext_vector_type(4)));
typedef float f32x4 __attribute__((ext_vector_type(4)));

static __device__ __forceinline__ float fexp2(float x) {
    return __builtin_amdgcn_exp2f(x);
}

#define LOG2E 1.44269504f
#define SHIFT2 28.8539008f   /* 20 * log2(e) */

// --------------------------------------------------------------------------
// K1: transpose + cvt x[b][c][n] f32 -> xt[b][n][c] f16.  64n x 64c tiles.
// Tail blocks (gid >= 2048) do the weight f32->f16 conversion (fused cvtw).
// --------------------------------------------------------------------------
__global__ __launch_bounds__(256) void transpose_kernel(
    const float* __restrict__ x, __half* __restrict__ xt,
    const float* __restrict__ fw, const float* __restrict__ gw,
    const float* __restrict__ hw, __half* __restrict__ wf16)
{
    const int gid = blockIdx.x;

    if (gid >= 2048) {
        int i = (gid - 2048) * 256 + threadIdx.x;
        float v;
        if (i < 8192)       v = fw[i];
        else if (i < 16384) v = gw[i - 8192];
        else                v = hw[i - 16384];
        wf16[i] = __float2half(v);
        return;
    }

    const int b = gid & 7, rest = gid >> 3;
    const int n0 = (rest & 63) * 64;
    const int c0 = (rest >> 6) * 64;
    const int tid = threadIdx.x;

    __shared__ float T[64 * 65];

    const float* xb = x + ((size_t)b * CC + c0) * NN + n0;
    const int u  = tid >> 4;          // 0..15
    const int n4 = (tid & 15) * 4;
#pragma unroll
    for (int r = 0; r < 4; ++r) {
        int c = r * 16 + u;
        f32x4 v = __builtin_nontemporal_load((const f32x4*)(xb + (size_t)c * NN + n4));
        T[c * 65 + n4 + 0] = v.x;
        T[c * 65 + n4 + 1] = v.y;
        T[c * 65 + n4 + 2] = v.z;
        T[c * 65 + n4 + 3] = v.w;
    }
    __syncthreads();

    const int lane = tid & 63, w = tid >> 6;
    const int n  = w * 16 + (lane >> 2);
    const int cc = (lane & 3) * 16;
    half8 o0, o1;
#pragma unroll
    for (int k = 0; k < 8; ++k) {
        o0[k] = (_Float16)T[(cc + k) * 65 + n];
        o1[k] = (_Float16)T[(cc + 8 + k) * 65 + n];
    }
    __half* dst = xt + ((size_t)b * NN + n0 + n) * CC + c0 + cc;
    *(half8*)(void*)dst = o0;
    *(half8*)(void*)(dst + 8) = o1;
}

// --------------------------------------------------------------------------
// K2: MFMA projections. 1D grid 2560: b = gid&7, then (nt 0..63, ot 0..4).
// --------------------------------------------------------------------------
__global__ __launch_bounds__(256) void proj_kernel(
    const __half* __restrict__ xt, const __half* __restrict__ wf16,
    const float* __restrict__ fb, const float* __restrict__ gb,
    const float* __restrict__ hb,
    __half* __restrict__ ft, __half* __restrict__ gt, __half* __restrict__ hm)
{
    const int tid = threadIdx.x;
    const int w = tid >> 6, lane = tid & 63, col = lane & 15, q = lane >> 4;
    const int gid = blockIdx.x;
    const int b = gid & 7, rest = gid >> 3;
    const int n0 = (rest & 63) * 64;
    const int ot = rest >> 6;          // 0..4

    const __half* xtb  = xt + (size_t)b * NN * CC;
    const __half* fw16 = wf16;
    const __half* gw16 = wf16 + 8192;
    const __half* hw16 = wf16 + 16384;

    f32x4 acc[4];
#pragma unroll
    for (int mt = 0; mt < 4; ++mt) acc[mt] = (f32x4){0.f, 0.f, 0.f, 0.f};

    if (ot == 0) {
        const int pix = n0 + 16 * w + col;
#pragma unroll
        for (int ks = 0; ks < 8; ++ks) {
            half8 bf = *(const half8*)(const void*)(xtb + (size_t)pix * CC + ks * 32 + q * 8);
#pragma unroll
            for (int mt = 0; mt < 4; ++mt) {
                const __half* wp = (mt < 2) ? (fw16 + (16 * mt + col) * CC)
                                            : (gw16 + (16 * (mt - 2) + col) * CC);
                half8 af = *(const half8*)(const void*)(wp + ks * 32 + q * 8);
                acc[mt] = __builtin_amdgcn_mfma_f32_16x16x32_f16(af, bf, acc[mt], 0, 0, 0);
            }
        }
#pragma unroll
        for (int mt = 0; mt < 4; ++mt) {
            const int mtl = mt & 1;
            const float* bsel = (mt < 2) ? fb : gb;
            __half* dsel = (mt < 2) ? ft : gt;
            half4v hv;
#pragma unroll
            for (int r = 0; r < 4; ++r)
                hv[r] = (_Float16)(acc[mt][r] + bsel[16 * mtl + 4 * q + r]);
            *(half4v*)(void*)(dsel + ((size_t)b * NN + pix) * CQ + 16 * mtl + 4 * q) = hv;
        }
    } else {
        const int c = (ot - 1) * 64 + 16 * w + col;
#pragma unroll
        for (int ks = 0; ks < 8; ++ks) {
            half8 bf = *(const half8*)(const void*)(hw16 + (size_t)c * CC + ks * 32 + q * 8);
#pragma unroll
            for (int mt = 0; mt < 4; ++mt) {
                half8 af = *(const half8*)(const void*)(xtb + (size_t)(n0 + 16 * mt + col) * CC + ks * 32 + q * 8);
                acc[mt] = __builtin_amdgcn_mfma_f32_16x16x32_f16(af, bf, acc[mt], 0, 0, 0);
            }
        }
        const float bias = hb[c];
#pragma unroll
        for (int mt = 0; mt < 4; ++mt) {
            half4v hv;
#pragma unroll
            for (int r = 0; r < 4; ++r)
                hv[r] = (_Float16)(acc[mt][r] + bias);
            *(half4v*)(void*)(hm + ((size_t)b * CC + c) * NN + n0 + 16 * mt + 4 * q) = hv;
        }
    }
}

// --------------------------------------------------------------------------
// K3: per-column softmax log-denominator with constant shift:
// shl[b][j] = -log2( sum_i exp2(S_ij*log2e - SHIFT2) ) - SHIFT2
// so pass2's P = exp2(S*log2e + shl[j]) = exp(S-20)/sum_i exp(S-20).
// --------------------------------------------------------------------------
__global__ __launch_bounds__(256) void pass1_kernel(
    const __half* __restrict__ ft, const __half* __restrict__ gt,
    float* __restrict__ shl)
{
    const int tid = threadIdx.x;
    const int w = tid >> 6, lane = tid & 63, col = lane & 15, q = lane >> 4;
    const int gid = blockIdx.x;
    const int b = gid & 7;
    const int jg = (gid >> 3) * 64 + 16 * w + col;

    const __half* fbase = ft + (size_t)b * NN * CQ;
    half8 gfrag = *(const half8*)(const void*)(gt + ((size_t)b * NN + jg) * CQ + q * 8);

    float a0 = 0.f, a1 = 0.f, a2 = 0.f, a3 = 0.f;
    const f32x4 zero = {0.f, 0.f, 0.f, 0.f};

    half8 a_cur = *(const half8*)(const void*)(fbase + (size_t)col * CQ + q * 8);
    for (int i0 = 0; i0 < NN; i0 += 16) {
        int i_n = (i0 + 16) & (NN - 1);
        half8 a_next = *(const half8*)(const void*)(fbase + (size_t)(i_n + col) * CQ + q * 8);
        f32x4 d = __builtin_amdgcn_mfma_f32_16x16x32_f16(a_cur, gfrag, zero, 0, 0, 0);
        a0 += fexp2(fmaf(d[0], LOG2E, -SHIFT2));
        a1 += fexp2(fmaf(d[1], LOG2E, -SHIFT2));
        a2 += fexp2(fmaf(d[2], LOG2E, -SHIFT2));
        a3 += fexp2(fmaf(d[3], LOG2E, -SHIFT2));
        a_cur = a_next;
    }
    float l = (a0 + a1) + (a2 + a3);
    l += __shfl_xor(l, 16);
    l += __shfl_xor(l, 32);
    if (q == 0)
        shl[(size_t)b * NN + jg] = -__log2f(l) - SHIFT2;
}

// --------------------------------------------------------------------------
// K4: O = h @ P^T + x.  Barrier-free, LDS-free.
// Block: 64 i x 256 c, 4 waves each own a 64-c slice; EVERY wave computes
// the full 64x64 S tile per j-step (x4 redundancy) and keeps P in regs.
// Grid 512 (b = gid&7): 2 blocks/CU, 2 waves/SIMD, free-running.
// Per j-step (64 j), per wave:
//   jt-loop x4: d[it] = mfma32(gfr[jt], ffr[it])  (S^T fragment)
//               pa[it] = f16(exp2(d*log2e + shl[j]))  -> x16 A-frag direct
//               acc[it][ns] += mfma16(pa[it], hv[ns][jt])
// hv (16 b64) + gfr (4 b128) double-buffered one full step ahead.
// --------------------------------------------------------------------------
__global__ __launch_bounds__(256, 2) void pass2_kernel(
    const float* __restrict__ x,
    const __half* __restrict__ ft, const __half* __restrict__ gt,
    const __half* __restrict__ hm, const float* __restrict__ shl,
    float* __restrict__ out)
{
    const int tid = threadIdx.x;
    const int w = tid >> 6, lane = tid & 63, col = lane & 15, q = lane >> 4;
    const int gid = blockIdx.x;
    const int b  = gid & 7;
    const int i0 = (gid >> 3) * 64;          // 64 i-tiles per batch
    const int cb = 64 * w;                   // wave c-slice: 64 channels

    const __half* gbase = gt + (size_t)b * NN * CQ;
    const __half* hbase = hm + (size_t)b * CC * NN;
    const float*  lb    = shl + (size_t)b * NN;

    // loop-invariant f B-frags (n = i)
    half8 ffr[4];
#pragma unroll
    for (int it = 0; it < 4; ++it)
        ffr[it] = *(const half8*)(const void*)(ft + ((size_t)b * NN + i0 + 16 * it + col) * CQ + q * 8);

    // hv row bases: c = cb+16ns+col, lane k-offset 4q
    const __half* hrow[4];
#pragma unroll
    for (int ns = 0; ns < 4; ++ns)
        hrow[ns] = hbase + (size_t)(cb + 16 * ns + col) * NN + 4 * q;

    f32x4 acc[4][4];
#pragma unroll
    for (int it = 0; it < 4; ++it)
#pragma unroll
        for (int ns = 0; ns < 4; ++ns)
            acc[it][ns] = (f32x4){0.f, 0.f, 0.f, 0.f};

    const f32x4 zero = {0.f, 0.f, 0.f, 0.f};

    // prologue: step-0 operands
    half8 gfr[4], gfr_n[4];
#pragma unroll
    for (int jt = 0; jt < 4; ++jt)
        gfr[jt] = *(const half8*)(const void*)(gbase + (size_t)(16 * jt + col) * CQ + q * 8);
    half4v hv[4][4], hv_n[4][4];
#pragma unroll
    for (int ns = 0; ns < 4; ++ns)
#pragma unroll
        for (int jt = 0; jt < 4; ++jt)
            hv[ns][jt] = *(const half4v*)(const void*)(hrow[ns] + 16 * jt);

    for (int j0 = 0; j0 < NN; j0 += 64) {
        const int jn = (j0 + 64) & (NN - 1);   // next-step prefetch (wraps)
#pragma unroll
        for (int jt = 0; jt < 4; ++jt) {
            // per-j log-denominator addend (L1-hot, 16KB/batch)
            f32x4 sl = *(const f32x4*)(lb + j0 + 16 * jt + 4 * q);

            // S^T: d[it] holds (i = 16it+col, j = j0+16jt+4q+r)
            f32x4 d[4];
#pragma unroll
            for (int it = 0; it < 4; ++it)
                d[it] = __builtin_amdgcn_mfma_f32_16x16x32_f16(gfr[jt], ffr[it], zero, 0, 0, 0);

            // stagger next-step prefetches into early jt slots
            if (jt == 0) {
#pragma unroll
                for (int k = 0; k < 4; ++k)
                    gfr_n[k] = *(const half8*)(const void*)(gbase + (size_t)(jn + 16 * k + col) * CQ + q * 8);
            }
            if (jt == 1) {
#pragma unroll
                for (int ns = 0; ns < 4; ++ns)
#pragma unroll
                    for (int k = 0; k < 4; ++k)
                        hv_n[ns][k] = *(const half4v*)(const void*)(hrow[ns] + jn + 16 * k);
            }

            // P = exp2(S*log2e + shl[j]) -> f16, direct x16 A-frag
            half4v pa[4];
#pragma unroll
            for (int it = 0; it < 4; ++it)
#pragma unroll
                for (int r = 0; r < 4; ++r)
                    pa[it][r] = (_Float16)fexp2(fmaf(d[it][r], LOG2E, sl[r]));

            // O: acc[it][ns] += P-frag x hv-frag  (16x16x16)
#pragma unroll
            for (int it = 0; it < 4; ++it)
#pragma unroll
                for (int ns = 0; ns < 4; ++ns)
                    acc[it][ns] = __builtin_amdgcn_mfma_f32_16x16x16f16(
                        pa[it], hv[ns][jt], acc[it][ns], 0, 0, 0);
        }
        // rotate double buffers
#pragma unroll
        for (int k = 0; k < 4; ++k) gfr[k] = gfr_n[k];
#pragma unroll
        for (int ns = 0; ns < 4; ++ns)
#pragma unroll
            for (int k = 0; k < 4; ++k) hv[ns][k] = hv_n[ns][k];
    }

    // epilogue: out = O + x; acc[it][ns][r] = O[i = i0+16it+4q+r][c = cb+16ns+col]
    const float* xb = x + (size_t)b * CC * NN;
    float* ob = out + (size_t)b * CC * NN;
#pragma unroll
    for (int it = 0; it < 4; ++it) {
#pragma unroll
        for (int ns = 0; ns < 4; ++ns) {
            int c  = cb + 16 * ns + col;
            int ii = i0 + 16 * it + 4 * q;
            size_t off = (size_t)c * NN + ii;
            f32x4 xv = __builtin_nontemporal_load((const f32x4*)(xb + off));
            f32x4 ov;
            ov.x = acc[it][ns][0] + xv.x;
            ov.y = acc[it][ns][1] + xv.y;
            ov.z = acc[it][ns][2] + xv.z;
            ov.w = acc[it][ns][3] + xv.w;
            __builtin_nontemporal_store(ov, (f32x4*)(ob + off));
        }
    }
}

// ---------------------------------------------------------------------------
extern "C" void kernel_launch(void* const* d_in, const int* in_sizes, int n_in,
                              void* d_out, int out_size, void* d_ws, size_t ws_size,
                              hipStream_t stream)
{
    const float* x  = (const float*)d_in[0];
    const float* fw = (const float*)d_in[1];
    const float* fb = (const float*)d_in[2];
    const float* gw = (const float*)d_in[3];
    const float* gb = (const float*)d_in[4];
    const float* hw = (const float*)d_in[5];
    const float* hb = (const float*)d_in[6];
    float* out = (float*)d_out;

    char* ws = (char*)d_ws;
    __half* xt = (__half*)(ws);                          // 16,777,216
    __half* wf = (__half*)(ws + (size_t)16777216);       //    163,840 (pad 256K)
    __half* ft = (__half*)(ws + (size_t)17039360);       //  2,097,152
    __half* gt = (__half*)(ws + (size_t)19136512);       //  2,097,152
    __half* hm = (__half*)(ws + (size_t)21233664);       // 16,777,216
    float*  lv = (float*) (ws + (size_t)38010880);       //    131,072

    transpose_kernel<<<dim3(2368), dim3(256), 0, stream>>>(x, xt, fw, gw, hw, wf);
    proj_kernel<<<dim3(2560), dim3(256), 0, stream>>>(xt, wf, fb, gb, hb, ft, gt, hm);
    pass1_kernel<<<dim3(512), dim3(256), 0, stream>>>(ft, gt, lv);
    pass2_kernel<<<dim3(512), dim3(256), 0, stream>>>(x, ft, gt, hm, lv, out);
}

// Round 4
// 331.151 us; speedup vs baseline: 1.4266x; 1.4266x over previous
//
#include <hip/hip_runtime.h>
#include <hip/hip_fp16.h>
#include <cmath>

// ---------------------------------------------------------------------------
// Self_Attention: B=8, C=256, C_=32, H=W=64, N=4096, GAMMA=1.0
// R8 = R5 structure + 8-wave work-sharing pass2 (no duplication):
//   - block 512 thr, grid 512 -> 2 blocks/CU, 16 waves/CU, 4 waves/SIMD
//   - O-phase: pure c-split (wave w owns c 32w..32w+31) -> hm traffic
//     identical to R5 (32KB/block-step), no cross-wave reduce
//   - S-phase: duty groups (waves 0-3 even steps, 4-7 odd) write P[(t+1)&1]
//     while all waves compute O(t) from P[t&1] -> S once per (i,j), exp of
//     t+1 overlaps O-MFMAs of t, convoy broken, 1 barrier/step
//   - LDS P layout + XOR swizzle byte-identical to R5 (proven conflict floor)
//   - pass1 stores shl[j] = -log2(l) - SHIFT2 (folded into exp2 addend)
// ws: xt 16M | wf 256K | ft 2M | gt 2M | hm 16M | shl 128K
// ---------------------------------------------------------------------------

#define BN 8
#define CC 256
#define CQ 32
#define NN 4096

typedef _Float16 half8 __attribute__((ext_vector_type(8)));
typedef _Float16 half4v __attribute__((ext_vector_type(4)));
typedef float f32x4 __attribute__((ext_vector_type(4)));

static __device__ __forceinline__ float fexp2(float x) {
    return __builtin_amdgcn_exp2f(x);
}

#define LOG2E 1.44269504f
#define SHIFT2 28.8539008f   /* 20 * log2(e) */

// --------------------------------------------------------------------------
// K1: transpose + cvt x[b][c][n] f32 -> xt[b][n][c] f16.  64n x 64c tiles.
// Tail blocks (gid >= 2048) do the weight f32->f16 conversion (fused cvtw).
// --------------------------------------------------------------------------
__global__ __launch_bounds__(256) void transpose_kernel(
    const float* __restrict__ x, __half* __restrict__ xt,
    const float* __restrict__ fw, const float* __restrict__ gw,
    const float* __restrict__ hw, __half* __restrict__ wf16)
{
    const int gid = blockIdx.x;

    if (gid >= 2048) {
        int i = (gid - 2048) * 256 + threadIdx.x;
        float v;
        if (i < 8192)       v = fw[i];
        else if (i < 16384) v = gw[i - 8192];
        else                v = hw[i - 16384];
        wf16[i] = __float2half(v);
        return;
    }

    const int b = gid & 7, rest = gid >> 3;
    const int n0 = (rest & 63) * 64;
    const int c0 = (rest >> 6) * 64;
    const int tid = threadIdx.x;

    __shared__ float T[64 * 65];

    const float* xb = x + ((size_t)b * CC + c0) * NN + n0;
    const int u  = tid >> 4;          // 0..15
    const int n4 = (tid & 15) * 4;
#pragma unroll
    for (int r = 0; r < 4; ++r) {
        int c = r * 16 + u;
        f32x4 v = __builtin_nontemporal_load((const f32x4*)(xb + (size_t)c * NN + n4));
        T[c * 65 + n4 + 0] = v.x;
        T[c * 65 + n4 + 1] = v.y;
        T[c * 65 + n4 + 2] = v.z;
        T[c * 65 + n4 + 3] = v.w;
    }
    __syncthreads();

    const int lane = tid & 63, w = tid >> 6;
    const int n  = w * 16 + (lane >> 2);
    const int cc = (lane & 3) * 16;
    half8 o0, o1;
#pragma unroll
    for (int k = 0; k < 8; ++k) {
        o0[k] = (_Float16)T[(cc + k) * 65 + n];
        o1[k] = (_Float16)T[(cc + 8 + k) * 65 + n];
    }
    __half* dst = xt + ((size_t)b * NN + n0 + n) * CC + c0 + cc;
    *(half8*)(void*)dst = o0;
    *(half8*)(void*)(dst + 8) = o1;
}

// --------------------------------------------------------------------------
// K2: MFMA projections. 1D grid 2560: b = gid&7, then (nt 0..63, ot 0..4).
// --------------------------------------------------------------------------
__global__ __launch_bounds__(256) void proj_kernel(
    const __half* __restrict__ xt, const __half* __restrict__ wf16,
    const float* __restrict__ fb, const float* __restrict__ gb,
    const float* __restrict__ hb,
    __half* __restrict__ ft, __half* __restrict__ gt, __half* __restrict__ hm)
{
    const int tid = threadIdx.x;
    const int w = tid >> 6, lane = tid & 63, col = lane & 15, q = lane >> 4;
    const int gid = blockIdx.x;
    const int b = gid & 7, rest = gid >> 3;
    const int n0 = (rest & 63) * 64;
    const int ot = rest >> 6;          // 0..4

    const __half* xtb  = xt + (size_t)b * NN * CC;
    const __half* fw16 = wf16;
    const __half* gw16 = wf16 + 8192;
    const __half* hw16 = wf16 + 16384;

    f32x4 acc[4];
#pragma unroll
    for (int mt = 0; mt < 4; ++mt) acc[mt] = (f32x4){0.f, 0.f, 0.f, 0.f};

    if (ot == 0) {
        const int pix = n0 + 16 * w + col;
#pragma unroll
        for (int ks = 0; ks < 8; ++ks) {
            half8 bf = *(const half8*)(const void*)(xtb + (size_t)pix * CC + ks * 32 + q * 8);
#pragma unroll
            for (int mt = 0; mt < 4; ++mt) {
                const __half* wp = (mt < 2) ? (fw16 + (16 * mt + col) * CC)
                                            : (gw16 + (16 * (mt - 2) + col) * CC);
                half8 af = *(const half8*)(const void*)(wp + ks * 32 + q * 8);
                acc[mt] = __builtin_amdgcn_mfma_f32_16x16x32_f16(af, bf, acc[mt], 0, 0, 0);
            }
        }
#pragma unroll
        for (int mt = 0; mt < 4; ++mt) {
            const int mtl = mt & 1;
            const float* bsel = (mt < 2) ? fb : gb;
            __half* dsel = (mt < 2) ? ft : gt;
            half4v hv;
#pragma unroll
            for (int r = 0; r < 4; ++r)
                hv[r] = (_Float16)(acc[mt][r] + bsel[16 * mtl + 4 * q + r]);
            *(half4v*)(void*)(dsel + ((size_t)b * NN + pix) * CQ + 16 * mtl + 4 * q) = hv;
        }
    } else {
        const int c = (ot - 1) * 64 + 16 * w + col;
#pragma unroll
        for (int ks = 0; ks < 8; ++ks) {
            half8 bf = *(const half8*)(const void*)(hw16 + (size_t)c * CC + ks * 32 + q * 8);
#pragma unroll
            for (int mt = 0; mt < 4; ++mt) {
                half8 af = *(const half8*)(const void*)(xtb + (size_t)(n0 + 16 * mt + col) * CC + ks * 32 + q * 8);
                acc[mt] = __builtin_amdgcn_mfma_f32_16x16x32_f16(af, bf, acc[mt], 0, 0, 0);
            }
        }
        const float bias = hb[c];
#pragma unroll
        for (int mt = 0; mt < 4; ++mt) {
            half4v hv;
#pragma unroll
            for (int r = 0; r < 4; ++r)
                hv[r] = (_Float16)(acc[mt][r] + bias);
            *(half4v*)(void*)(hm + ((size_t)b * CC + c) * NN + n0 + 16 * mt + 4 * q) = hv;
        }
    }
}

// --------------------------------------------------------------------------
// K3: per-column softmax log-denominator with constant shift:
// shl[b][j] = -log2( sum_i exp2(S_ij*log2e - SHIFT2) ) - SHIFT2
// so pass2's P = exp2(S*log2e + shl[j]).
// --------------------------------------------------------------------------
__global__ __launch_bounds__(256) void pass1_kernel(
    const __half* __restrict__ ft, const __half* __restrict__ gt,
    float* __restrict__ shl)
{
    const int tid = threadIdx.x;
    const int w = tid >> 6, lane = tid & 63, col = lane & 15, q = lane >> 4;
    const int gid = blockIdx.x;
    const int b = gid & 7;
    const int jg = (gid >> 3) * 64 + 16 * w + col;

    const __half* fbase = ft + (size_t)b * NN * CQ;
    half8 gfrag = *(const half8*)(const void*)(gt + ((size_t)b * NN + jg) * CQ + q * 8);

    float a0 = 0.f, a1 = 0.f, a2 = 0.f, a3 = 0.f;
    const f32x4 zero = {0.f, 0.f, 0.f, 0.f};

    half8 a_cur = *(const half8*)(const void*)(fbase + (size_t)col * CQ + q * 8);
    for (int i0 = 0; i0 < NN; i0 += 16) {
        int i_n = (i0 + 16) & (NN - 1);
        half8 a_next = *(const half8*)(const void*)(fbase + (size_t)(i_n + col) * CQ + q * 8);
        f32x4 d = __builtin_amdgcn_mfma_f32_16x16x32_f16(a_cur, gfrag, zero, 0, 0, 0);
        a0 += fexp2(fmaf(d[0], LOG2E, -SHIFT2));
        a1 += fexp2(fmaf(d[1], LOG2E, -SHIFT2));
        a2 += fexp2(fmaf(d[2], LOG2E, -SHIFT2));
        a3 += fexp2(fmaf(d[3], LOG2E, -SHIFT2));
        a_cur = a_next;
    }
    float l = (a0 + a1) + (a2 + a3);
    l += __shfl_xor(l, 16);
    l += __shfl_xor(l, 32);
    if (q == 0)
        shl[(size_t)b * NN + jg] = -__log2f(l) - SHIFT2;
}

// --------------------------------------------------------------------------
// K4: O = h @ P^T + x.  Block: 64 i x 256 c, 8 waves, j-step 64.
// Grid 512 (b = gid&7): 2 blocks/CU, 16 waves/CU, 4 waves/SIMD.
// O-phase (all 8 waves): wave w owns c-slice 32w; per step 8 swizzled b128
// A-reads from P[t&1] : 16 MFMA (ms=4, ns=2, ks=2).  No i-split -> hm
// traffic = R5 (32KB/block-step), no cross-wave reduce.
// S-phase (duty pipeline): waves 0-3 produce P for even steps, waves 4-7
// for odd steps; duty wave computes 16 j x 64 i (4 MFMA + exp) and writes
// P[(t+1)&1] while O(t) runs from P[t&1].  S computed once per (i,j).
// One barrier per step; P buffers alternate (WAR separated by the barrier).
// --------------------------------------------------------------------------
__global__ __launch_bounds__(512, 4) void pass2_kernel(
    const float* __restrict__ x,
    const __half* __restrict__ ft, const __half* __restrict__ gt,
    const __half* __restrict__ hm, const float* __restrict__ shl,
    float* __restrict__ out)
{
    const int tid = threadIdx.x;
    const int w = tid >> 6, lane = tid & 63, col = lane & 15, q = lane >> 4;
    const int gid = blockIdx.x;
    const int b  = gid & 7;
    const int i0 = (gid >> 3) * 64;          // 64 i-tiles per batch
    const int sg  = w >> 2;                  // S-duty group (0: even P, 1: odd P)
    const int sw4 = w & 3;                   // j-sub slot within duty quad
    const int cb  = 32 * w;                  // O-phase c-slice (8 x 32 = 256)

    __shared__ __half P[2][64 * 64];

    const __half* gbase = gt + (size_t)b * NN * CQ;
    const __half* hbase = hm + (size_t)b * CC * NN;
    const float*  lb    = shl + (size_t)b * NN;

    // loop-invariant f B-frags (n = i), shared by all waves
    half8 ffr[4];
#pragma unroll
    for (int it = 0; it < 4; ++it)
        ffr[it] = *(const half8*)(const void*)(ft + ((size_t)b * NN + i0 + 16 * it + col) * CQ + q * 8);

    // hv row bases for this wave's c-slice
    const __half* hrow[2];
#pragma unroll
    for (int ns = 0; ns < 2; ++ns)
        hrow[ns] = hbase + (size_t)(cb + 16 * ns + col) * NN + q * 8;

    f32x4 acc[4][2];
#pragma unroll
    for (int it = 0; it < 4; ++it)
#pragma unroll
        for (int ns = 0; ns < 2; ++ns)
            acc[it][ns] = (f32x4){0.f, 0.f, 0.f, 0.f};

    const f32x4 zero = {0.f, 0.f, 0.f, 0.f};
    const int sw  = 8 * (col & 7);           // P XOR swizzle (R5-identical)
    const int jsl = 16 * sw4 + 4 * q;        // duty lane's j offset in range

    // gfr for this wave's first duty range (group 0: range 0, group 1: range 1)
    half8 gfr = *(const half8*)(const void*)(
        gbase + (size_t)(sg * 64 + 16 * sw4 + col) * CQ + q * 8);

    // prologue: group 0 computes S(range 0) -> P[0]; prefetch range 2
    if (sg == 0) {
        f32x4 sl = *(const f32x4*)(lb + jsl);
        f32x4 d[4];
#pragma unroll
        for (int it = 0; it < 4; ++it)
            d[it] = __builtin_amdgcn_mfma_f32_16x16x32_f16(gfr, ffr[it], zero, 0, 0, 0);
        gfr = *(const half8*)(const void*)(
            gbase + (size_t)(128 + 16 * sw4 + col) * CQ + q * 8);
#pragma unroll
        for (int it = 0; it < 4; ++it) {
            half4v pv;
#pragma unroll
            for (int r = 0; r < 4; ++r)
                pv[r] = (_Float16)fexp2(fmaf(d[it][r], LOG2E, sl[r]));
            *(half4v*)(void*)(&P[0][0] + (16 * it + col) * 64 + (jsl ^ sw)) = pv;
        }
    }
    __syncthreads();

    for (int t = 0; t < 64; ++t) {
        const int j0 = t * 64;
        const __half* Pr = &P[t & 1][0];

        // hv loads for this step (L2-resident hm; issued early for distance)
        half8 hv[2][2];
#pragma unroll
        for (int ns = 0; ns < 2; ++ns)
#pragma unroll
            for (int ks = 0; ks < 2; ++ks)
                hv[ns][ks] = *(const half8*)(const void*)(hrow[ns] + j0 + ks * 32);

        // S-phase for step t+1 (duty group only; wave-uniform branch)
        const bool duty = (((t + 1) & 1) == sg) && (t < 63);
        f32x4 d[4];
        f32x4 sl;
        if (duty) {
            sl = *(const f32x4*)(lb + (t + 1) * 64 + jsl);
#pragma unroll
            for (int it = 0; it < 4; ++it)
                d[it] = __builtin_amdgcn_mfma_f32_16x16x32_f16(gfr, ffr[it], zero, 0, 0, 0);
            // prefetch gfr for next duty (range t+3)
            const int rn = (t + 3) & 63;
            gfr = *(const half8*)(const void*)(
                gbase + (size_t)(rn * 64 + 16 * sw4 + col) * CQ + q * 8);
        }

        // O-phase: A = P[t&1] (swizzled b128), B = hv
        __builtin_amdgcn_s_setprio(1);
#pragma unroll
        for (int ks = 0; ks < 2; ++ks) {
            half8 af[4];
#pragma unroll
            for (int it = 0; it < 4; ++it)
                af[it] = *(const half8*)(const void*)(
                    Pr + (16 * it + col) * 64 + ((ks * 32 + q * 8) ^ sw));
#pragma unroll
            for (int it = 0; it < 4; ++it)
#pragma unroll
                for (int ns = 0; ns < 2; ++ns)
                    acc[it][ns] = __builtin_amdgcn_mfma_f32_16x16x32_f16(
                        af[it], hv[ns][ks], acc[it][ns], 0, 0, 0);
        }
        __builtin_amdgcn_s_setprio(0);

        // exp + write P[(t+1)&1] (duty group; overlaps other waves' O tail)
        if (duty) {
            __half* Pw = &P[(t + 1) & 1][0];
#pragma unroll
            for (int it = 0; it < 4; ++it) {
                half4v pv;
#pragma unroll
                for (int r = 0; r < 4; ++r)
                    pv[r] = (_Float16)fexp2(fmaf(d[it][r], LOG2E, sl[r]));
                *(half4v*)(void*)(Pw + (16 * it + col) * 64 + (jsl ^ sw)) = pv;
            }
        }
        __syncthreads();
    }

    // epilogue: out = O + x (nontemporal both ways; GAMMA = 1)
    const float* xb = x + (size_t)b * CC * NN;
    float* ob = out + (size_t)b * CC * NN;
#pragma unroll
    for (int it = 0; it < 4; ++it) {
#pragma unroll
        for (int ns = 0; ns < 2; ++ns) {
            int c  = cb + 16 * ns + col;
            int ii = i0 + 16 * it + 4 * q;
            size_t off = (size_t)c * NN + ii;
            f32x4 xv = __builtin_nontemporal_load((const f32x4*)(xb + off));
            f32x4 ov;
            ov.x = acc[it][ns][0] + xv.x;
            ov.y = acc[it][ns][1] + xv.y;
            ov.z = acc[it][ns][2] + xv.z;
            ov.w = acc[it][ns][3] + xv.w;
            __builtin_nontemporal_store(ov, (f32x4*)(ob + off));
        }
    }
}

// ---------------------------------------------------------------------------
extern "C" void kernel_launch(void* const* d_in, const int* in_sizes, int n_in,
                              void* d_out, int out_size, void* d_ws, size_t ws_size,
                              hipStream_t stream)
{
    const float* x  = (const float*)d_in[0];
    const float* fw = (const float*)d_in[1];
    const float* fb = (const float*)d_in[2];
    const float* gw = (const float*)d_in[3];
    const float* gb = (const float*)d_in[4];
    const float* hw = (const float*)d_in[5];
    const float* hb = (const float*)d_in[6];
    float* out = (float*)d_out;

    char* ws = (char*)d_ws;
    __half* xt = (__half*)(ws);                          // 16,777,216
    __half* wf = (__half*)(ws + (size_t)16777216);       //    163,840 (pad 256K)
    __half* ft = (__half*)(ws + (size_t)17039360);       //  2,097,152
    __half* gt = (__half*)(ws + (size_t)19136512);       //  2,097,152
    __half* hm = (__half*)(ws + (size_t)21233664);       // 16,777,216
    float*  lv = (float*) (ws + (size_t)38010880);       //    131,072

    transpose_kernel<<<dim3(2368), dim3(256), 0, stream>>>(x, xt, fw, gw, hw, wf);
    proj_kernel<<<dim3(2560), dim3(256), 0, stream>>>(xt, wf, fb, gb, hb, ft, gt, hm);
    pass1_kernel<<<dim3(512), dim3(256), 0, stream>>>(ft, gt, lv);
    pass2_kernel<<<dim3(512), dim3(512), 0, stream>>>(x, ft, gt, hm, lv, out);
}

// Round 5
// 329.465 us; speedup vs baseline: 1.4339x; 1.0051x over previous
//
#include <hip/hip_runtime.h>
#include <hip/hip_fp16.h>
#include <cmath>

// ---------------------------------------------------------------------------
// Self_Attention: B=8, C=256, C_=32, H=W=64, N=4096, GAMMA=1.0
// R9 = R8 with pass2 de-serialized (R8 showed occupancy 2x -> 0 gain, so the
// wall is the phase-locked step pipeline, not latency):
//   1. hv(t+1) register-prefetched BEFORE the O-MFMA cluster of step t
//      (L2 latency hidden under MFMA issue, not naked after the barrier)
//   2. symmetric S-duty: ALL 8 waves do S each step (wave = i-half x j-quad,
//      2 MFMA + 8 exp + 2 writes) -> uniform barrier arrival, no stragglers
//   3. everything proven kept byte-identical: pitch-64 XOR swizzle, c-split
//      O-phase (no hm dup), setprio, 1 barrier/step, LB(512,4)
// pass1: 2x i-unroll (2 independent MFMAs in flight).
// ws: xt 16M | wf 256K | ft 2M | gt 2M | hm 16M | shl 128K
// ---------------------------------------------------------------------------

#define BN 8
#define CC 256
#define CQ 32
#define NN 4096

typedef _Float16 half8 __attribute__((ext_vector_type(8)));
typedef _Float16 half4v __attribute__((ext_vector_type(4)));
typedef float f32x4 __attribute__((ext_vector_type(4)));

static __device__ __forceinline__ float fexp2(float x) {
    return __builtin_amdgcn_exp2f(x);
}

#define LOG2E 1.44269504f
#define SHIFT2 28.8539008f   /* 20 * log2(e) */

// --------------------------------------------------------------------------
// K1: transpose + cvt x[b][c][n] f32 -> xt[b][n][c] f16.  64n x 64c tiles.
// Tail blocks (gid >= 2048) do the weight f32->f16 conversion (fused cvtw).
// --------------------------------------------------------------------------
__global__ __launch_bounds__(256) void transpose_kernel(
    const float* __restrict__ x, __half* __restrict__ xt,
    const float* __restrict__ fw, const float* __restrict__ gw,
    const float* __restrict__ hw, __half* __restrict__ wf16)
{
    const int gid = blockIdx.x;

    if (gid >= 2048) {
        int i = (gid - 2048) * 256 + threadIdx.x;
        float v;
        if (i < 8192)       v = fw[i];
        else if (i < 16384) v = gw[i - 8192];
        else                v = hw[i - 16384];
        wf16[i] = __float2half(v);
        return;
    }

    const int b = gid & 7, rest = gid >> 3;
    const int n0 = (rest & 63) * 64;
    const int c0 = (rest >> 6) * 64;
    const int tid = threadIdx.x;

    __shared__ float T[64 * 65];

    const float* xb = x + ((size_t)b * CC + c0) * NN + n0;
    const int u  = tid >> 4;          // 0..15
    const int n4 = (tid & 15) * 4;
#pragma unroll
    for (int r = 0; r < 4; ++r) {
        int c = r * 16 + u;
        f32x4 v = __builtin_nontemporal_load((const f32x4*)(xb + (size_t)c * NN + n4));
        T[c * 65 + n4 + 0] = v.x;
        T[c * 65 + n4 + 1] = v.y;
        T[c * 65 + n4 + 2] = v.z;
        T[c * 65 + n4 + 3] = v.w;
    }
    __syncthreads();

    const int lane = tid & 63, w = tid >> 6;
    const int n  = w * 16 + (lane >> 2);
    const int cc = (lane & 3) * 16;
    half8 o0, o1;
#pragma unroll
    for (int k = 0; k < 8; ++k) {
        o0[k] = (_Float16)T[(cc + k) * 65 + n];
        o1[k] = (_Float16)T[(cc + 8 + k) * 65 + n];
    }
    __half* dst = xt + ((size_t)b * NN + n0 + n) * CC + c0 + cc;
    *(half8*)(void*)dst = o0;
    *(half8*)(void*)(dst + 8) = o1;
}

// --------------------------------------------------------------------------
// K2: MFMA projections. 1D grid 2560: b = gid&7, then (nt 0..63, ot 0..4).
// --------------------------------------------------------------------------
__global__ __launch_bounds__(256) void proj_kernel(
    const __half* __restrict__ xt, const __half* __restrict__ wf16,
    const float* __restrict__ fb, const float* __restrict__ gb,
    const float* __restrict__ hb,
    __half* __restrict__ ft, __half* __restrict__ gt, __half* __restrict__ hm)
{
    const int tid = threadIdx.x;
    const int w = tid >> 6, lane = tid & 63, col = lane & 15, q = lane >> 4;
    const int gid = blockIdx.x;
    const int b = gid & 7, rest = gid >> 3;
    const int n0 = (rest & 63) * 64;
    const int ot = rest >> 6;          // 0..4

    const __half* xtb  = xt + (size_t)b * NN * CC;
    const __half* fw16 = wf16;
    const __half* gw16 = wf16 + 8192;
    const __half* hw16 = wf16 + 16384;

    f32x4 acc[4];
#pragma unroll
    for (int mt = 0; mt < 4; ++mt) acc[mt] = (f32x4){0.f, 0.f, 0.f, 0.f};

    if (ot == 0) {
        const int pix = n0 + 16 * w + col;
#pragma unroll
        for (int ks = 0; ks < 8; ++ks) {
            half8 bf = *(const half8*)(const void*)(xtb + (size_t)pix * CC + ks * 32 + q * 8);
#pragma unroll
            for (int mt = 0; mt < 4; ++mt) {
                const __half* wp = (mt < 2) ? (fw16 + (16 * mt + col) * CC)
                                            : (gw16 + (16 * (mt - 2) + col) * CC);
                half8 af = *(const half8*)(const void*)(wp + ks * 32 + q * 8);
                acc[mt] = __builtin_amdgcn_mfma_f32_16x16x32_f16(af, bf, acc[mt], 0, 0, 0);
            }
        }
#pragma unroll
        for (int mt = 0; mt < 4; ++mt) {
            const int mtl = mt & 1;
            const float* bsel = (mt < 2) ? fb : gb;
            __half* dsel = (mt < 2) ? ft : gt;
            half4v hv;
#pragma unroll
            for (int r = 0; r < 4; ++r)
                hv[r] = (_Float16)(acc[mt][r] + bsel[16 * mtl + 4 * q + r]);
            *(half4v*)(void*)(dsel + ((size_t)b * NN + pix) * CQ + 16 * mtl + 4 * q) = hv;
        }
    } else {
        const int c = (ot - 1) * 64 + 16 * w + col;
#pragma unroll
        for (int ks = 0; ks < 8; ++ks) {
            half8 bf = *(const half8*)(const void*)(hw16 + (size_t)c * CC + ks * 32 + q * 8);
#pragma unroll
            for (int mt = 0; mt < 4; ++mt) {
                half8 af = *(const half8*)(const void*)(xtb + (size_t)(n0 + 16 * mt + col) * CC + ks * 32 + q * 8);
                acc[mt] = __builtin_amdgcn_mfma_f32_16x16x32_f16(af, bf, acc[mt], 0, 0, 0);
            }
        }
        const float bias = hb[c];
#pragma unroll
        for (int mt = 0; mt < 4; ++mt) {
            half4v hv;
#pragma unroll
            for (int r = 0; r < 4; ++r)
                hv[r] = (_Float16)(acc[mt][r] + bias);
            *(half4v*)(void*)(hm + ((size_t)b * CC + c) * NN + n0 + 16 * mt + 4 * q) = hv;
        }
    }
}

// --------------------------------------------------------------------------
// K3: per-column softmax log-denominator with constant shift:
// shl[b][j] = -log2( sum_i exp2(S_ij*log2e - SHIFT2) ) - SHIFT2
// 2x i-unroll: two independent MFMAs in flight per iteration.
// --------------------------------------------------------------------------
__global__ __launch_bounds__(256) void pass1_kernel(
    const __half* __restrict__ ft, const __half* __restrict__ gt,
    float* __restrict__ shl)
{
    const int tid = threadIdx.x;
    const int w = tid >> 6, lane = tid & 63, col = lane & 15, q = lane >> 4;
    const int gid = blockIdx.x;
    const int b = gid & 7;
    const int jg = (gid >> 3) * 64 + 16 * w + col;

    const __half* fbase = ft + (size_t)b * NN * CQ;
    half8 gfrag = *(const half8*)(const void*)(gt + ((size_t)b * NN + jg) * CQ + q * 8);

    float a0 = 0.f, a1 = 0.f, a2 = 0.f, a3 = 0.f;
    const f32x4 zero = {0.f, 0.f, 0.f, 0.f};

    half8 a0v = *(const half8*)(const void*)(fbase + (size_t)col * CQ + q * 8);
    half8 a1v = *(const half8*)(const void*)(fbase + (size_t)(16 + col) * CQ + q * 8);
    for (int i0 = 0; i0 < NN; i0 += 32) {
        int i_n = (i0 + 32) & (NN - 1);
        half8 a2v = *(const half8*)(const void*)(fbase + (size_t)(i_n + col) * CQ + q * 8);
        half8 a3v = *(const half8*)(const void*)(fbase + (size_t)(i_n + 16 + col) * CQ + q * 8);
        f32x4 d0 = __builtin_amdgcn_mfma_f32_16x16x32_f16(a0v, gfrag, zero, 0, 0, 0);
        f32x4 d1 = __builtin_amdgcn_mfma_f32_16x16x32_f16(a1v, gfrag, zero, 0, 0, 0);
        a0 += fexp2(fmaf(d0[0], LOG2E, -SHIFT2)) + fexp2(fmaf(d1[0], LOG2E, -SHIFT2));
        a1 += fexp2(fmaf(d0[1], LOG2E, -SHIFT2)) + fexp2(fmaf(d1[1], LOG2E, -SHIFT2));
        a2 += fexp2(fmaf(d0[2], LOG2E, -SHIFT2)) + fexp2(fmaf(d1[2], LOG2E, -SHIFT2));
        a3 += fexp2(fmaf(d0[3], LOG2E, -SHIFT2)) + fexp2(fmaf(d1[3], LOG2E, -SHIFT2));
        a0v = a2v;
        a1v = a3v;
    }
    float l = (a0 + a1) + (a2 + a3);
    l += __shfl_xor(l, 16);
    l += __shfl_xor(l, 32);
    if (q == 0)
        shl[(size_t)b * NN + jg] = -__log2f(l) - SHIFT2;
}

// --------------------------------------------------------------------------
// K4: O = h @ P^T + x.  Block: 64 i x 256 c, 8 waves, j-step 64.
// Grid 512 (b = gid&7): 2 blocks/CU, 16 waves/CU, 4 waves/SIMD.
// Symmetric S-duty: every wave, every step, computes a 32i x 16j piece of
// S(t+1) (wave = (ih = w>>2 i-half) x (jq = w&3 j-quad)): 2 MFMA + 8 exp +
// 2 half4v writes.  Uniform barrier arrival.
// O-phase: wave w owns c-slice 32w; 8 swizzled b128 A-reads : 16 MFMA.
// hv(t+1) register-prefetched BEFORE the O-MFMA cluster (L2 latency hidden
// under ~600cyc of MFMA issue).  One barrier per step.
// --------------------------------------------------------------------------
__global__ __launch_bounds__(512, 4) void pass2_kernel(
    const float* __restrict__ x,
    const __half* __restrict__ ft, const __half* __restrict__ gt,
    const __half* __restrict__ hm, const float* __restrict__ shl,
    float* __restrict__ out)
{
    const int tid = threadIdx.x;
    const int w = tid >> 6, lane = tid & 63, col = lane & 15, q = lane >> 4;
    const int gid = blockIdx.x;
    const int b  = gid & 7;
    const int i0 = (gid >> 3) * 64;          // 64 i-tiles per batch
    const int ih = w >> 2;                   // S-duty i-half (0/1)
    const int jq = w & 3;                    // S-duty j-quad (16 j)
    const int cb = 32 * w;                   // O-phase c-slice (8 x 32 = 256)

    __shared__ __half P[2][64 * 64];

    const __half* gbase = gt + (size_t)b * NN * CQ;
    const __half* hbase = hm + (size_t)b * CC * NN;
    const float*  lb    = shl + (size_t)b * NN;

    // S-duty f B-frags: this wave's two i-tiles (i = 16*(2ih+t2)+col)
    half8 ffr2[2];
#pragma unroll
    for (int t2 = 0; t2 < 2; ++t2)
        ffr2[t2] = *(const half8*)(const void*)(
            ft + ((size_t)b * NN + i0 + 16 * (2 * ih + t2) + col) * CQ + q * 8);

    // hv row bases for this wave's c-slice
    const __half* hrow[2];
#pragma unroll
    for (int ns = 0; ns < 2; ++ns)
        hrow[ns] = hbase + (size_t)(cb + 16 * ns + col) * NN + q * 8;

    f32x4 acc[4][2];
#pragma unroll
    for (int it = 0; it < 4; ++it)
#pragma unroll
        for (int ns = 0; ns < 2; ++ns)
            acc[it][ns] = (f32x4){0.f, 0.f, 0.f, 0.f};

    const f32x4 zero = {0.f, 0.f, 0.f, 0.f};
    const int sw  = 8 * (col & 7);           // P XOR swizzle (proven layout)
    const int jsl = 16 * jq + 4 * q;         // duty lane's j offset in range

    // gfr: A-frag (m = j) for this wave's duty quad, range 0
    half8 gfr = *(const half8*)(const void*)(
        gbase + (size_t)(16 * jq + col) * CQ + q * 8);

    // prologue: all waves compute S(range 0) -> P[0]; advance gfr to range 1
    {
        f32x4 sl0 = *(const f32x4*)(lb + jsl);
        f32x4 d0[2];
#pragma unroll
        for (int t2 = 0; t2 < 2; ++t2)
            d0[t2] = __builtin_amdgcn_mfma_f32_16x16x32_f16(gfr, ffr2[t2], zero, 0, 0, 0);
        gfr = *(const half8*)(const void*)(
            gbase + (size_t)(64 + 16 * jq + col) * CQ + q * 8);
#pragma unroll
        for (int t2 = 0; t2 < 2; ++t2) {
            half4v pv;
#pragma unroll
            for (int r = 0; r < 4; ++r)
                pv[r] = (_Float16)fexp2(fmaf(d0[t2][r], LOG2E, sl0[r]));
            *(half4v*)(void*)(&P[0][0] + (16 * (2 * ih + t2) + col) * 64 + (jsl ^ sw)) = pv;
        }
    }
    // hv for step 0
    half8 hv[2][2];
#pragma unroll
    for (int ns = 0; ns < 2; ++ns)
#pragma unroll
        for (int ks = 0; ks < 2; ++ks)
            hv[ns][ks] = *(const half8*)(const void*)(hrow[ns] + ks * 32);
    __syncthreads();

    for (int t = 0; t < 64; ++t) {
        const int j0 = t * 64;
        const __half* Pr = &P[t & 1][0];
        const bool duty = (t < 63);

        // S-phase for step t+1 (all waves; gfr holds range t+1)
        f32x4 d2[2];
        f32x4 sl;
        if (duty) {
            sl = *(const f32x4*)(lb + (t + 1) * 64 + jsl);
#pragma unroll
            for (int t2 = 0; t2 < 2; ++t2)
                d2[t2] = __builtin_amdgcn_mfma_f32_16x16x32_f16(gfr, ffr2[t2], zero, 0, 0, 0);
            const int rn = (t + 2) & 63;
            gfr = *(const half8*)(const void*)(
                gbase + (size_t)(rn * 64 + 16 * jq + col) * CQ + q * 8);
        }

        // hv(t+1) prefetch -- issued BEFORE the O-MFMA cluster
        const int jn = (j0 + 64) & (NN - 1);
        half8 hv_n[2][2];
#pragma unroll
        for (int ns = 0; ns < 2; ++ns)
#pragma unroll
            for (int ks = 0; ks < 2; ++ks)
                hv_n[ns][ks] = *(const half8*)(const void*)(hrow[ns] + jn + ks * 32);

        // O-phase: A = P[t&1] (swizzled b128), B = hv (prefetched last step)
        __builtin_amdgcn_s_setprio(1);
#pragma unroll
        for (int ks = 0; ks < 2; ++ks) {
            half8 af[4];
#pragma unroll
            for (int it = 0; it < 4; ++it)
                af[it] = *(const half8*)(const void*)(
                    Pr + (16 * it + col) * 64 + ((ks * 32 + q * 8) ^ sw));
#pragma unroll
            for (int it = 0; it < 4; ++it)
#pragma unroll
                for (int ns = 0; ns < 2; ++ns)
                    acc[it][ns] = __builtin_amdgcn_mfma_f32_16x16x32_f16(
                        af[it], hv[ns][ks], acc[it][ns], 0, 0, 0);
        }
        __builtin_amdgcn_s_setprio(0);

        // exp + write P[(t+1)&1]
        if (duty) {
            __half* Pw = &P[(t + 1) & 1][0];
#pragma unroll
            for (int t2 = 0; t2 < 2; ++t2) {
                half4v pv;
#pragma unroll
                for (int r = 0; r < 4; ++r)
                    pv[r] = (_Float16)fexp2(fmaf(d2[t2][r], LOG2E, sl[r]));
                *(half4v*)(void*)(Pw + (16 * (2 * ih + t2) + col) * 64 + (jsl ^ sw)) = pv;
            }
        }
        __syncthreads();

        // rotate hv double buffer
#pragma unroll
        for (int ns = 0; ns < 2; ++ns)
#pragma unroll
            for (int ks = 0; ks < 2; ++ks)
                hv[ns][ks] = hv_n[ns][ks];
    }

    // epilogue: out = O + x (nontemporal both ways; GAMMA = 1)
    const float* xb = x + (size_t)b * CC * NN;
    float* ob = out + (size_t)b * CC * NN;
#pragma unroll
    for (int it = 0; it < 4; ++it) {
#pragma unroll
        for (int ns = 0; ns < 2; ++ns) {
            int c  = cb + 16 * ns + col;
            int ii = i0 + 16 * it + 4 * q;
            size_t off = (size_t)c * NN + ii;
            f32x4 xv = __builtin_nontemporal_load((const f32x4*)(xb + off));
            f32x4 ov;
            ov.x = acc[it][ns][0] + xv.x;
            ov.y = acc[it][ns][1] + xv.y;
            ov.z = acc[it][ns][2] + xv.z;
            ov.w = acc[it][ns][3] + xv.w;
            __builtin_nontemporal_store(ov, (f32x4*)(ob + off));
        }
    }
}

// ---------------------------------------------------------------------------
extern "C" void kernel_launch(void* const* d_in, const int* in_sizes, int n_in,
                              void* d_out, int out_size, void* d_ws, size_t ws_size,
                              hipStream_t stream)
{
    const float* x  = (const float*)d_in[0];
    const float* fw = (const float*)d_in[1];
    const float* fb = (const float*)d_in[2];
    const float* gw = (const float*)d_in[3];
    const float* gb = (const float*)d_in[4];
    const float* hw = (const float*)d_in[5];
    const float* hb = (const float*)d_in[6];
    float* out = (float*)d_out;

    char* ws = (char*)d_ws;
    __half* xt = (__half*)(ws);                          // 16,777,216
    __half* wf = (__half*)(ws + (size_t)16777216);       //    163,840 (pad 256K)
    __half* ft = (__half*)(ws + (size_t)17039360);       //  2,097,152
    __half* gt = (__half*)(ws + (size_t)19136512);       //  2,097,152
    __half* hm = (__half*)(ws + (size_t)21233664);       // 16,777,216
    float*  lv = (float*) (ws + (size_t)38010880);       //    131,072

    transpose_kernel<<<dim3(2368), dim3(256), 0, stream>>>(x, xt, fw, gw, hw, wf);
    proj_kernel<<<dim3(2560), dim3(256), 0, stream>>>(xt, wf, fb, gb, hb, ft, gt, hm);
    pass1_kernel<<<dim3(512), dim3(256), 0, stream>>>(ft, gt, lv);
    pass2_kernel<<<dim3(512), dim3(512), 0, stream>>>(x, ft, gt, hm, lv, out);
}